// Round 2
// baseline (44913.058 us; speedup 1.0000x reference)
//
#include <hip/hip_runtime.h>

// DNADecoder: B=64,T=128,P=1024,D=512,F=2048,V=4096,L=4
// Sequential 128-step decode; cross-attn collapses to a per-(layer,batch)
// constant; self-attn folds to x@(WvWo+I)+(bvWo+bo); argmax(softmax)=argmax.
// All tensors fp32 (per reference dtypes). Output fp32 probs [B,T,V].

#define B 64
#define T 128
#define PP 1024
#define D 512
#define F 2048
#define V 4096
#define XP 20   // padded row-stride (floats) for transposed LDS tiles

typedef const float* fp;

static __device__ __forceinline__ float wred(float s){
    #pragma unroll
    for (int o = 32; o > 0; o >>= 1) s += __shfl_xor(s, o, 64);
    return s;
}

// ---------------- setup: protein -> mem1 -> per-layer cross-attn constant ----
__global__ __launch_bounds__(256) void k_setup_mem(
    fp prot, fp p1w, fp p1b, fp p2w, fp p2b,
    fp caw, fp cab, float* ca_out)
{
    __shared__ float xp[PP];
    __shared__ float hr[PP];
    __shared__ float m1[D];
    __shared__ float tv[D];
    int b = blockIdx.x, tid = threadIdx.x;
    for (int i = tid; i < PP; i += 256) xp[i] = prot[b*PP + i];
    __syncthreads();
    for (int c = tid; c < 1024; c += 256){
        float acc = p1b[c];
        for (int k = 0; k < PP; k++) acc = fmaf(xp[k], p1w[k*1024 + c], acc);
        hr[c] = fmaxf(acc, 0.f);
    }
    __syncthreads();
    for (int c = tid; c < D; c += 256){
        float acc = p2b[c];
        for (int k = 0; k < 1024; k++) acc = fmaf(hr[k], p2w[k*D + c], acc);
        m1[c] = acc;
    }
    __syncthreads();
    for (int l = 0; l < 4; l++){
        const float* wv = caw + (size_t)(l*4 + 2)*D*D;
        const float* bv = cab + (l*4 + 2)*D;
        for (int c = tid; c < D; c += 256){
            float acc = bv[c];
            for (int k = 0; k < D; k++) acc = fmaf(m1[k], wv[k*D + c], acc);
            tv[c] = acc;
        }
        __syncthreads();
        const float* wo = caw + (size_t)(l*4 + 3)*D*D;
        const float* bo = cab + (l*4 + 3)*D;
        for (int c = tid; c < D; c += 256){
            float acc = bo[c];
            for (int k = 0; k < D; k++) acc = fmaf(tv[k], wo[k*D + c], acc);
            ca_out[(l*B + b)*D + c] = acc;
        }
        __syncthreads();
    }
}

// ---------------- setup: fold self-attn  Wfold = Wv@Wo + I, bfold = bv@Wo+bo --
__global__ __launch_bounds__(256) void k_fold_sa(
    fp saw, fp sab, float* wfold, float* bfold)
{
    int l = blockIdx.x >> 6;
    int kb = blockIdx.x & 63;              // 8 rows of Wfold each
    int tid = threadIdx.x;
    const float* Wv = saw + (size_t)(l*4 + 2)*D*D;
    const float* Wo = saw + (size_t)(l*4 + 3)*D*D;
    __shared__ float a[8][D];
    for (int i = tid; i < 8*D; i += 256){
        int r = i >> 9, m = i & 511;
        a[r][m] = Wv[(kb*8 + r)*D + m];
    }
    __syncthreads();
    for (int cc = 0; cc < 2; cc++){
        int c = tid + cc*256;
        float acc[8];
        #pragma unroll
        for (int r = 0; r < 8; r++) acc[r] = 0.f;
        for (int m = 0; m < D; m++){
            float w = Wo[m*D + c];
            #pragma unroll
            for (int r = 0; r < 8; r++) acc[r] = fmaf(a[r][m], w, acc[r]);
        }
        #pragma unroll
        for (int r = 0; r < 8; r++){
            int kg = kb*8 + r;
            wfold[((size_t)l*D + kg)*D + c] = acc[r] + (kg == c ? 1.f : 0.f);
        }
    }
    if (kb == 0){
        const float* bv = sab + (l*4 + 2)*D;
        const float* bo = sab + (l*4 + 3)*D;
        for (int c = tid; c < D; c += 256){
            float acc = bo[c];
            for (int m = 0; m < D; m++) acc = fmaf(bv[m], Wo[m*D + c], acc);
            bfold[l*D + c] = acc;
        }
    }
}

// ---------- prologues: build transposed padded LDS x^T tile for 16 rows -------
// xt holds d in [d0,d0+256), layout xt[(d-d0)*XP + rr], 16 rows starting r0.

static __device__ void pro_emb(float* xt, const int* tok, fp emb, fp pe,
                               int t, int r0, int d0, int tid)
{
    int lane = tid & 63, wid = tid >> 6;
    for (int i = 0; i < 4; i++){
        int rr = wid*4 + i;
        int tk = tok[r0 + rr];
        const float* er = emb + (size_t)tk*D + d0;
        const float* pr = pe + t*D + d0;
        #pragma unroll
        for (int j = 0; j < 4; j++){
            int d = lane + j*64;
            xt[d*XP + rr] = er[d] + pr[d];
        }
    }
}

// x = LN(sum of 4 partials of U3) * g + b   (consumer-side LN)
static __device__ void pro_ln4(float* xt, const float* u3, fp g, fp bb,
                               int r0, int d0, int tid)
{
    int lane = tid & 63, wid = tid >> 6;
    int jb = d0 >> 6;
    for (int i = 0; i < 4; i++){
        int rr = wid*4 + i, r = r0 + rr;
        float e[8]; float s = 0.f, sq = 0.f;
        #pragma unroll
        for (int j = 0; j < 8; j++){
            int d = lane + j*64;
            float v = u3[r*D + d] + u3[B*D + r*D + d]
                    + u3[2*B*D + r*D + d] + u3[3*B*D + r*D + d];
            e[j] = v; s += v; sq += v*v;
        }
        s = wred(s); sq = wred(sq);
        float mu = s*(1.f/D);
        float rs = rsqrtf(sq*(1.f/D) - mu*mu + 1e-5f);
        #pragma unroll
        for (int j = 0; j < 8; j++){
            int d = lane + j*64;
            if (j >= jb && j < jb + 4)
                xt[(d - d0)*XP + rr] = (e[j]-mu)*rs*g[d] + bb[d];
        }
    }
}

// z = LN1( LN0(u1p0+u1p1)*g0+b0 + ca ) * g1 + b1
// writes transposed slice xt (if non-null) and/or column block zc[16][64]
static __device__ void pro_ln2(float* xt, float* zc, const float* u1, const float* ca,
                               fp g0, fp b0, fp g1, fp b1,
                               int r0, int d0, int c0, int tid)
{
    int lane = tid & 63, wid = tid >> 6;
    int jb = d0 >> 6, jc = c0 >> 6;
    for (int i = 0; i < 4; i++){
        int rr = wid*4 + i, r = r0 + rr;
        float e[8]; float s = 0.f, sq = 0.f;
        #pragma unroll
        for (int j = 0; j < 8; j++){
            int d = lane + j*64;
            float v = u1[r*D + d] + u1[B*D + r*D + d];
            e[j] = v; s += v; sq += v*v;
        }
        s = wred(s); sq = wred(sq);
        float mu = s*(1.f/D), rs = rsqrtf(sq*(1.f/D) - mu*mu + 1e-5f);
        s = 0.f; sq = 0.f;
        #pragma unroll
        for (int j = 0; j < 8; j++){
            int d = lane + j*64;
            float v = (e[j]-mu)*rs*g0[d] + b0[d] + ca[r*D + d];
            e[j] = v; s += v; sq += v*v;
        }
        s = wred(s); sq = wred(sq);
        mu = s*(1.f/D); rs = rsqrtf(sq*(1.f/D) - mu*mu + 1e-5f);
        #pragma unroll
        for (int j = 0; j < 8; j++){
            int d = lane + j*64;
            float z = (e[j]-mu)*rs*g1[d] + b1[d];
            if (xt && j >= jb && j < jb + 4) xt[(d - d0)*XP + rr] = z;
            if (zc && j == jc) zc[rr*64 + lane] = z;
        }
    }
}

// ---------------- per-step stage kernels -------------------------------------

// U1 = x @ Wfold + bfold  (x from emb lookup at l==0, else LN of prev U3)
__global__ __launch_bounds__(256) void k_sa(
    const float* wfold, const float* bfold, const float* u3,
    fp lng, fp lnb, const int* tok, fp emb, fp pe,
    float* u1, int l, int t)
{
    __shared__ float xt[256*XP];
    int bx = blockIdx.x;                    // 64 = 8cb x 4rbg x 2ks
    int cb = bx & 7, rbg = (bx >> 3) & 3, ks = bx >> 5;
    int tid = threadIdx.x;
    int r0 = rbg*16, d0 = ks*256;
    if (l == 0) pro_emb(xt, tok, emb, pe, t, r0, d0, tid);
    else        pro_ln4(xt, u3, lng + ((l-1)*3+2)*D, lnb + ((l-1)*3+2)*D, r0, d0, tid);
    __syncthreads();
    int lane = tid & 63, rb = tid >> 6;
    int c = cb*64 + lane;
    const float* W = wfold + (size_t)l*D*D + (size_t)d0*D + c;
    float bias = (ks == 0) ? bfold[l*D + c] : 0.f;
    float a0=bias, a1=bias, a2=bias, a3=bias;
    const float* xc = xt + rb*4;
    #pragma unroll 8
    for (int k = 0; k < 256; k++){
        float w = W[(size_t)k*D];
        float4 xv = *(const float4*)(xc + k*XP);
        a0 = fmaf(xv.x, w, a0); a1 = fmaf(xv.y, w, a1);
        a2 = fmaf(xv.z, w, a2); a3 = fmaf(xv.w, w, a3);
    }
    int r = r0 + rb*4;
    float* o = u1 + ks*B*D;
    o[(r+0)*D + c] = a0; o[(r+1)*D + c] = a1;
    o[(r+2)*D + c] = a2; o[(r+3)*D + c] = a3;
}

// H(partial) = z @ W1   (relu applied by consumer after partial sum)
__global__ __launch_bounds__(256) void k_ffn1(
    const float* u1, const float* ca, fp lng, fp lnb,
    fp w1, fp b1, float* h, int l)
{
    __shared__ float zt[256*XP];
    int bx = blockIdx.x;                    // 256 = 32cb x 4rbg x 2ks
    int cb = bx & 31, rbg = (bx >> 5) & 3, ks = bx >> 7;
    int tid = threadIdx.x;
    int r0 = rbg*16, d0 = ks*256;
    pro_ln2(zt, nullptr, u1, ca + l*B*D,
            lng + l*3*D, lnb + l*3*D, lng + (l*3+1)*D, lnb + (l*3+1)*D,
            r0, d0, 0, tid);
    __syncthreads();
    int lane = tid & 63, rb = tid >> 6;
    int c = cb*64 + lane;
    const float* W = w1 + (size_t)l*D*F + (size_t)d0*F + c;
    float bias = (ks == 0) ? b1[l*F + c] : 0.f;
    float a0=bias, a1=bias, a2=bias, a3=bias;
    const float* xc = zt + rb*4;
    #pragma unroll 8
    for (int k = 0; k < 256; k++){
        float w = W[(size_t)k*F];
        float4 xv = *(const float4*)(xc + k*XP);
        a0 = fmaf(xv.x, w, a0); a1 = fmaf(xv.y, w, a1);
        a2 = fmaf(xv.z, w, a2); a3 = fmaf(xv.w, w, a3);
    }
    int r = r0 + rb*4;
    float* o = h + ks*B*F;
    o[(r+0)*F + c] = a0; o[(r+1)*F + c] = a1;
    o[(r+2)*F + c] = a2; o[(r+3)*F + c] = a3;
}

// U3(partial) = z + relu(H) @ W2 + b2   (z/bias added only by kh==0)
__global__ __launch_bounds__(256) void k_ffn2(
    const float* u1, const float* ca, fp lng, fp lnb,
    const float* h, fp w2, fp b2, float* u3, int l)
{
    __shared__ float ht[512*XP];
    __shared__ float zc[16*64];
    int bx = blockIdx.x;                    // 128 = 8cb x 4rbg x 4kh
    int cb = bx & 7, rbg = (bx >> 3) & 3, kh = bx >> 5;
    int tid = threadIdx.x;
    int r0 = rbg*16, c0 = cb*64;
    if (kh == 0)
        pro_ln2(nullptr, zc, u1, ca + l*B*D,
                lng + l*3*D, lnb + l*3*D, lng + (l*3+1)*D, lnb + (l*3+1)*D,
                r0, 0, c0, tid);
    for (int i = tid; i < 16*512; i += 256){
        int rr = i >> 9, kk = i & 511;
        int gi = (r0+rr)*F + kh*512 + kk;
        ht[kk*XP + rr] = fmaxf(h[gi] + h[B*F + gi], 0.f);
    }
    __syncthreads();
    int lane = tid & 63, rb = tid >> 6;
    int c = c0 + lane;
    const float* W = w2 + (size_t)l*F*D + (size_t)kh*512*D + c;
    float a0, a1, a2, a3;
    if (kh == 0){
        float bb = b2[l*D + c];
        a0 = bb + zc[(rb*4+0)*64 + lane];
        a1 = bb + zc[(rb*4+1)*64 + lane];
        a2 = bb + zc[(rb*4+2)*64 + lane];
        a3 = bb + zc[(rb*4+3)*64 + lane];
    } else { a0=a1=a2=a3=0.f; }
    const float* xc = ht + rb*4;
    #pragma unroll 8
    for (int k = 0; k < 512; k++){
        float w = W[(size_t)k*D];
        float4 xv = *(const float4*)(xc + k*XP);
        a0 = fmaf(xv.x, w, a0); a1 = fmaf(xv.y, w, a1);
        a2 = fmaf(xv.z, w, a2); a3 = fmaf(xv.w, w, a3);
    }
    int r = r0 + rb*4;
    float* o = u3 + kh*B*D;
    o[(r+0)*D + c] = a0; o[(r+1)*D + c] = a1;
    o[(r+2)*D + c] = a2; o[(r+3)*D + c] = a3;
}

// logits(partial) = LN(U3 L3) @ out_w + out_b
__global__ __launch_bounds__(256) void k_logits(
    const float* u3, fp lng, fp lnb, fp outw, fp outb, float* lgt)
{
    __shared__ float xt[256*XP];
    int bx = blockIdx.x;                    // 512 = 64cb x 4rbg x 2ks
    int cb = bx & 63, rbg = (bx >> 6) & 3, ks = bx >> 8;
    int tid = threadIdx.x;
    int r0 = rbg*16, d0 = ks*256;
    pro_ln4(xt, u3, lng + 11*D, lnb + 11*D, r0, d0, tid);
    __syncthreads();
    int lane = tid & 63, rb = tid >> 6;
    int c = cb*64 + lane;
    const float* W = outw + (size_t)d0*V + c;
    float bias = (ks == 0) ? outb[c] : 0.f;
    float a0=bias, a1=bias, a2=bias, a3=bias;
    const float* xc = xt + rb*4;
    #pragma unroll 8
    for (int k = 0; k < 256; k++){
        float w = W[(size_t)k*V];
        float4 xv = *(const float4*)(xc + k*XP);
        a0 = fmaf(xv.x, w, a0); a1 = fmaf(xv.y, w, a1);
        a2 = fmaf(xv.z, w, a2); a3 = fmaf(xv.w, w, a3);
    }
    int r = r0 + rb*4;
    float* o = lgt + ks*B*V;
    o[(r+0)*V + c] = a0; o[(r+1)*V + c] = a1;
    o[(r+2)*V + c] = a2; o[(r+3)*V + c] = a3;
}

// softmax -> probs (fp32 out), argmax -> next token
__global__ __launch_bounds__(256) void k_final(
    const float* lgt, float* out, int* tok, int t)
{
    int b = blockIdx.x, tid = threadIdx.x;
    int lane = tid & 63, wid = tid >> 6;
    __shared__ float sm[4]; __shared__ int si[4]; __shared__ float ss[4];
    const float* l0 = lgt + b*V;
    const float* l1 = lgt + B*V + b*V;
    float m = -3.4e38f; int mi = 0;
    for (int i = tid; i < V; i += 256){
        float v = l0[i] + l1[i];
        if (v > m){ m = v; mi = i; }
    }
    #pragma unroll
    for (int o = 32; o > 0; o >>= 1){
        float om = __shfl_xor(m, o, 64);
        int   oi = __shfl_xor(mi, o, 64);
        if (om > m || (om == m && oi < mi)){ m = om; mi = oi; }
    }
    if (lane == 0){ sm[wid] = m; si[wid] = mi; }
    __syncthreads();
    if (tid == 0){
        #pragma unroll
        for (int w = 1; w < 4; w++)
            if (sm[w] > sm[0] || (sm[w] == sm[0] && si[w] < si[0])){ sm[0]=sm[w]; si[0]=si[w]; }
        tok[b] = si[0];
    }
    __syncthreads();
    m = sm[0];
    float s = 0.f;
    for (int i = tid; i < V; i += 256) s += expf(l0[i] + l1[i] - m);
    s = wred(s);
    if (lane == 0) ss[wid] = s;
    __syncthreads();
    float inv = 1.f / (ss[0] + ss[1] + ss[2] + ss[3]);
    float* orow = out + ((size_t)b*T + t)*V;
    for (int i = tid; i < V; i += 256)
        orow[i] = expf(l0[i] + l1[i] - m) * inv;
}

// ---------------------------------------------------------------------------
extern "C" void kernel_launch(void* const* d_in, const int* in_sizes, int n_in,
                              void* d_out, int out_size, void* d_ws, size_t ws_size,
                              hipStream_t stream)
{
    fp prot = (fp)d_in[0];
    const int* itok = (const int*)d_in[1];
    fp p1w=(fp)d_in[2], p1b=(fp)d_in[3], p2w=(fp)d_in[4], p2b=(fp)d_in[5];
    fp emb=(fp)d_in[6], saw=(fp)d_in[7], sab=(fp)d_in[8];
    fp caw=(fp)d_in[9], cab=(fp)d_in[10];
    fp w1=(fp)d_in[11], b1=(fp)d_in[12], w2=(fp)d_in[13], b2=(fp)d_in[14];
    fp lng=(fp)d_in[15], lnb=(fp)d_in[16];
    fp outw=(fp)d_in[17], outb=(fp)d_in[18], pe=(fp)d_in[19];

    char* w = (char*)d_ws;
    float* wfold = (float*)w;  w += (size_t)4*D*D*4;   // 4 MB
    float* bfold = (float*)w;  w += 4*D*4;
    float* ca_o  = (float*)w;  w += 4*B*D*4;
    float* u1    = (float*)w;  w += 2*B*D*4;           // 2 K-partials
    float* hbuf  = (float*)w;  w += 2*B*F*4;           // 2 K-partials
    float* u3    = (float*)w;  w += 4*B*D*4;           // 4 K-partials
    float* lgt   = (float*)w;  w += 2*B*V*4;           // 2 K-partials
    int*   tok   = (int*)w;    w += 256;

    float* out = (float*)d_out;

    k_setup_mem<<<64, 256, 0, stream>>>(prot, p1w, p1b, p2w, p2b, caw, cab, ca_o);
    k_fold_sa<<<256, 256, 0, stream>>>(saw, sab, wfold, bfold);

    for (int t = 0; t < T; t++){
        const int* tsrc = (t == 0) ? itok : tok;
        for (int l = 0; l < 4; l++){
            k_sa  <<<64,  256, 0, stream>>>(wfold, bfold, u3, lng, lnb, tsrc, emb, pe, u1, l, t);
            k_ffn1<<<256, 256, 0, stream>>>(u1, ca_o, lng, lnb, w1, b1, hbuf, l);
            k_ffn2<<<128, 256, 0, stream>>>(u1, ca_o, lng, lnb, hbuf, w2, b2, u3, l);
        }
        k_logits<<<512, 256, 0, stream>>>(u3, lng, lnb, outw, outb, lgt);
        k_final <<<64,  256, 0, stream>>>(lgt, out, tok, t);
    }
}